// Round 1
// baseline (139.105 us; speedup 1.0000x reference)
//
#include <hip/hip_runtime.h>
#include <hip/hip_bf16.h>
#include <stdint.h>

// FGN layer: out = (x@W^T + bias) * exp(-( x^2@ic2^T - 2 x@(c*ic2)^T + d ))
// bias_i = -sum_j W_ij C_ij ; d_i = sum_j C_ij^2 ic2_ij ; ic2 = inv_covar^2
// Strategy: bf16 MFMA (threshold is bf16-class), 2 accumulator sets (l, g),
// g folds its two GEMMs into one accumulator (different A operands x, x^2).

typedef __attribute__((ext_vector_type(8))) __bf16 bf16x8;
typedef __attribute__((ext_vector_type(4))) float f32x4;

__device__ __forceinline__ unsigned short f2bf(float f) {
  union { float f; unsigned int u; } v; v.f = f;
  unsigned int u = v.u;
  unsigned int r = (u + 0x7FFFu + ((u >> 16) & 1u)) >> 16;  // RNE
  return (unsigned short)r;
}

// One wave per output-feature row: convert W -> bf16, build ic2 and -2*c*ic2
// in bf16, and reduce bias_i / d_i in fp32.
__global__ __launch_bounds__(256) void prep_rows(
    const float* __restrict__ W, const float* __restrict__ C,
    const float* __restrict__ IC,
    unsigned short* __restrict__ Wb, unsigned short* __restrict__ I2b,
    unsigned short* __restrict__ M2b,
    float* __restrict__ bias, float* __restrict__ dvec) {
  const int wave = threadIdx.x >> 6;
  const int lane = threadIdx.x & 63;
  const int row  = blockIdx.x * 4 + wave;   // 1024 blocks * 4 rows = 4096
  const float4* W4 = (const float4*)W + (size_t)row * 256;
  const float4* C4 = (const float4*)C + (size_t)row * 256;
  const float4* I4 = (const float4*)IC + (size_t)row * 256;
  ushort4* Wo = (ushort4*)Wb + (size_t)row * 256;
  ushort4* Io = (ushort4*)I2b + (size_t)row * 256;
  ushort4* Mo = (ushort4*)M2b + (size_t)row * 256;
  float swc = 0.f, sd = 0.f;
#pragma unroll
  for (int p = 0; p < 4; ++p) {
    int idx = lane + p * 64;
    float4 w = W4[idx], c = C4[idx], ic = I4[idx];
    float i2x = ic.x * ic.x, i2y = ic.y * ic.y, i2z = ic.z * ic.z, i2w = ic.w * ic.w;
    swc += w.x * c.x + w.y * c.y + w.z * c.z + w.w * c.w;
    sd  += c.x * c.x * i2x + c.y * c.y * i2y + c.z * c.z * i2z + c.w * c.w * i2w;
    ushort4 a, b, m;
    a.x = f2bf(w.x); a.y = f2bf(w.y); a.z = f2bf(w.z); a.w = f2bf(w.w);
    b.x = f2bf(i2x); b.y = f2bf(i2y); b.z = f2bf(i2z); b.w = f2bf(i2w);
    m.x = f2bf(-2.f * c.x * i2x); m.y = f2bf(-2.f * c.y * i2y);
    m.z = f2bf(-2.f * c.z * i2z); m.w = f2bf(-2.f * c.w * i2w);
    Wo[idx] = a; Io[idx] = b; Mo[idx] = m;
  }
#pragma unroll
  for (int off = 32; off > 0; off >>= 1) {
    swc += __shfl_down(swc, off);
    sd  += __shfl_down(sd, off);
  }
  if (lane == 0) { bias[row] = -swc; dvec[row] = sd; }
}

// x -> bf16(x), bf16(x^2)
__global__ __launch_bounds__(256) void prep_x(
    const float* __restrict__ X,
    unsigned short* __restrict__ Xb, unsigned short* __restrict__ Qb) {
  int idx = blockIdx.x * 256 + threadIdx.x;   // 262144 float4s total
  float4 x = ((const float4*)X)[idx];
  ushort4 a, b;
  a.x = f2bf(x.x); a.y = f2bf(x.y); a.z = f2bf(x.z); a.w = f2bf(x.w);
  b.x = f2bf(x.x * x.x); b.y = f2bf(x.y * x.y);
  b.z = f2bf(x.z * x.z); b.w = f2bf(x.w * x.w);
  ((ushort4*)Xb)[idx] = a;
  ((ushort4*)Qb)[idx] = b;
}

#define GLD16(gp, lp)                                                          \
  __builtin_amdgcn_global_load_lds(                                            \
      (const __attribute__((address_space(1))) unsigned int*)(gp),             \
      (__attribute__((address_space(3))) unsigned int*)(lp), 16, 0, 0)

// Tile: M=64 (batch), N=128 (out features), BK=32. 256 threads = 4 waves,
// wave tile 32x64 (2 m-tiles x 4 n-tiles of 16x16). Grid (32 n, 16 m):
// linear blockIdx % 8 == n-tile % 8 -> same-N blocks share an XCD's L2.
__global__ __launch_bounds__(256) void fgn_gemm(
    const unsigned short* __restrict__ Xb, const unsigned short* __restrict__ Qb,
    const unsigned short* __restrict__ Wb, const unsigned short* __restrict__ I2b,
    const unsigned short* __restrict__ M2b,
    const float* __restrict__ bias, const float* __restrict__ dvec,
    float* __restrict__ out) {
  __shared__ unsigned short sx[64 * 32];    // 4 KB
  __shared__ unsigned short sq[64 * 32];    // 4 KB
  __shared__ unsigned short sw[128 * 32];   // 8 KB
  __shared__ unsigned short si[128 * 32];   // 8 KB
  __shared__ unsigned short sm[128 * 32];   // 8 KB
  const int t = threadIdx.x;
  const int m0 = blockIdx.y * 64;
  const int n0 = blockIdx.x * 128;

  // global->LDS staging: thread t loads 16B: row t/4, col-block (t%3)*8
  const int arow = t >> 2;
  const int acol = (t & 3) * 8;
  const unsigned short* gx  = Xb  + (size_t)(m0 + arow) * 1024 + acol;
  const unsigned short* gq  = Qb  + (size_t)(m0 + arow) * 1024 + acol;
  const unsigned short* gw0 = Wb  + (size_t)(n0 + arow) * 1024 + acol;
  const unsigned short* gw1 = Wb  + (size_t)(n0 + 64 + arow) * 1024 + acol;
  const unsigned short* gi0 = I2b + (size_t)(n0 + arow) * 1024 + acol;
  const unsigned short* gi1 = I2b + (size_t)(n0 + 64 + arow) * 1024 + acol;
  const unsigned short* gm0 = M2b + (size_t)(n0 + arow) * 1024 + acol;
  const unsigned short* gm1 = M2b + (size_t)(n0 + 64 + arow) * 1024 + acol;

  const int wave = t >> 6, lane = t & 63;
  const int wm = (wave & 1) * 32;   // wave m offset
  const int wn = (wave >> 1) * 64;  // wave n offset
  const int fm = lane & 15;         // fragment row/col
  const int q  = lane >> 4;         // k-quad

  f32x4 accL[2][4], accG[2][4];
#pragma unroll
  for (int mt = 0; mt < 2; ++mt)
#pragma unroll
    for (int nt = 0; nt < 4; ++nt) { accL[mt][nt] = (f32x4)0.f; accG[mt][nt] = (f32x4)0.f; }

  for (int k0 = 0; k0 < 1024; k0 += 32) {
    __syncthreads();  // previous iteration's LDS reads done
    GLD16(gx,  &sx[t * 8]);
    GLD16(gq,  &sq[t * 8]);
    GLD16(gw0, &sw[t * 8]);
    GLD16(gw1, &sw[2048 + t * 8]);
    GLD16(gi0, &si[t * 8]);
    GLD16(gi1, &si[2048 + t * 8]);
    GLD16(gm0, &sm[t * 8]);
    GLD16(gm1, &sm[2048 + t * 8]);
    gx += 32; gq += 32; gw0 += 32; gw1 += 32;
    gi0 += 32; gi1 += 32; gm0 += 32; gm1 += 32;
    __syncthreads();  // compiler emits vmcnt(0) drain before barrier

    bf16x8 ax[2], aq[2], bw[4], bi[4], bm[4];
#pragma unroll
    for (int mt = 0; mt < 2; ++mt) {
      int r = wm + mt * 16 + fm;
      ax[mt] = *(const bf16x8*)&sx[r * 32 + q * 8];
      aq[mt] = *(const bf16x8*)&sq[r * 32 + q * 8];
    }
#pragma unroll
    for (int nt = 0; nt < 4; ++nt) {
      int r = wn + nt * 16 + fm;
      bw[nt] = *(const bf16x8*)&sw[r * 32 + q * 8];
      bi[nt] = *(const bf16x8*)&si[r * 32 + q * 8];
      bm[nt] = *(const bf16x8*)&sm[r * 32 + q * 8];
    }
#pragma unroll
    for (int mt = 0; mt < 2; ++mt)
#pragma unroll
      for (int nt = 0; nt < 4; ++nt) {
        accL[mt][nt] = __builtin_amdgcn_mfma_f32_16x16x32_bf16(ax[mt], bw[nt], accL[mt][nt], 0, 0, 0);
        accG[mt][nt] = __builtin_amdgcn_mfma_f32_16x16x32_bf16(aq[mt], bi[nt], accG[mt][nt], 0, 0, 0);
        accG[mt][nt] = __builtin_amdgcn_mfma_f32_16x16x32_bf16(ax[mt], bm[nt], accG[mt][nt], 0, 0, 0);
      }
  }

  // epilogue: out = (accL + bias) * exp(-(accG + d))
  // C/D layout: col = lane&15, row = (lane>>4)*4 + reg  [verified m89/m91]
#pragma unroll
  for (int nt = 0; nt < 4; ++nt) {
    int gcol = n0 + wn + nt * 16 + fm;
    float bn = bias[gcol], dn = dvec[gcol];
#pragma unroll
    for (int mt = 0; mt < 2; ++mt) {
      int growb = m0 + wm + mt * 16 + q * 4;
#pragma unroll
      for (int r = 0; r < 4; ++r) {
        float l = accL[mt][nt][r] + bn;
        float g = accG[mt][nt][r] + dn;
        out[(size_t)(growb + r) * 4096 + gcol] = l * __expf(-g);
      }
    }
  }
}

extern "C" void kernel_launch(void* const* d_in, const int* in_sizes, int n_in,
                              void* d_out, int out_size, void* d_ws, size_t ws_size,
                              hipStream_t stream) {
  const float* x  = (const float*)d_in[0];
  const float* W  = (const float*)d_in[1];
  const float* C  = (const float*)d_in[2];
  const float* IC = (const float*)d_in[3];
  float* out = (float*)d_out;

  char* ws = (char*)d_ws;
  unsigned short* Wb  = (unsigned short*)(ws);                          // 8 MB
  unsigned short* I2b = (unsigned short*)(ws + (8u << 20));             // 8 MB
  unsigned short* M2b = (unsigned short*)(ws + (16u << 20));            // 8 MB
  unsigned short* Xb  = (unsigned short*)(ws + (24u << 20));            // 2 MB
  unsigned short* Qb  = (unsigned short*)(ws + (26u << 20));            // 2 MB
  float* bias = (float*)(ws + (28u << 20));                             // 16 KB
  float* dvec = (float*)(ws + (28u << 20) + 16384);                     // 16 KB

  hipLaunchKernelGGL(prep_rows, dim3(1024), dim3(256), 0, stream, W, C, IC,
                     Wb, I2b, M2b, bias, dvec);
  hipLaunchKernelGGL(prep_x, dim3(1024), dim3(256), 0, stream, x, Xb, Qb);
  hipLaunchKernelGGL(fgn_gemm, dim3(32, 16), dim3(256), 0, stream,
                     Xb, Qb, Wb, I2b, M2b, bias, dvec, out);
}

// Round 2
// 138.271 us; speedup vs baseline: 1.0060x; 1.0060x over previous
//
#include <hip/hip_runtime.h>
#include <hip/hip_bf16.h>
#include <stdint.h>

// FGN layer: out = (x@W^T + bias) * exp(-( x^2@ic2^T + x@(-2c*ic2)^T + d ))
// bias_i = -sum_j W_ij C_ij ; d_i = sum_j C_ij^2 ic2_ij ; ic2 = inv_covar^2
// R1: bf16 MFMA validated (absmax 16 / thr 60.8). R2: 32x32x16 MFMA,
// 128x128 block / 64x64 wave tile, XOR-swizzled LDS (kill 8-way conflicts),
// explicit double-buffered global_load_lds prefetch (1 block/CU).

typedef __attribute__((ext_vector_type(8))) __bf16 bf16x8;
typedef __attribute__((ext_vector_type(16))) float f32x16;

__device__ __forceinline__ unsigned short f2bf(float f) {
  union { float f; unsigned int u; } v; v.f = f;
  unsigned int u = v.u;
  unsigned int r = (u + 0x7FFFu + ((u >> 16) & 1u)) >> 16;  // RNE
  return (unsigned short)r;
}

// Merged prep: blocks 0..1023 handle the 4096 O-rows (4 rows/block, one
// wave each): convert W -> bf16, build ic2 and -2*c*ic2 in bf16, reduce
// bias/d in fp32. Blocks 1024..1279: x -> bf16(x), bf16(x^2).
__global__ __launch_bounds__(256) void prep(
    const float* __restrict__ X, const float* __restrict__ W,
    const float* __restrict__ C, const float* __restrict__ IC,
    unsigned short* __restrict__ Wb, unsigned short* __restrict__ I2b,
    unsigned short* __restrict__ M2b,
    unsigned short* __restrict__ Xb, unsigned short* __restrict__ Qb,
    float* __restrict__ bias, float* __restrict__ dvec) {
  const int b = blockIdx.x;
  if (b < 1024) {
    const int wave = threadIdx.x >> 6;
    const int lane = threadIdx.x & 63;
    const int row  = b * 4 + wave;
    const float4* W4 = (const float4*)W + (size_t)row * 256;
    const float4* C4 = (const float4*)C + (size_t)row * 256;
    const float4* I4 = (const float4*)IC + (size_t)row * 256;
    ushort4* Wo = (ushort4*)Wb + (size_t)row * 256;
    ushort4* Io = (ushort4*)I2b + (size_t)row * 256;
    ushort4* Mo = (ushort4*)M2b + (size_t)row * 256;
    float swc = 0.f, sd = 0.f;
#pragma unroll
    for (int p = 0; p < 4; ++p) {
      int idx = lane + p * 64;
      float4 w = W4[idx], c = C4[idx], ic = I4[idx];
      float i2x = ic.x * ic.x, i2y = ic.y * ic.y, i2z = ic.z * ic.z, i2w = ic.w * ic.w;
      swc += w.x * c.x + w.y * c.y + w.z * c.z + w.w * c.w;
      sd  += c.x * c.x * i2x + c.y * c.y * i2y + c.z * c.z * i2z + c.w * c.w * i2w;
      ushort4 a, bb, m;
      a.x = f2bf(w.x); a.y = f2bf(w.y); a.z = f2bf(w.z); a.w = f2bf(w.w);
      bb.x = f2bf(i2x); bb.y = f2bf(i2y); bb.z = f2bf(i2z); bb.w = f2bf(i2w);
      m.x = f2bf(-2.f * c.x * i2x); m.y = f2bf(-2.f * c.y * i2y);
      m.z = f2bf(-2.f * c.z * i2z); m.w = f2bf(-2.f * c.w * i2w);
      Wo[idx] = a; Io[idx] = bb; Mo[idx] = m;
    }
#pragma unroll
    for (int off = 32; off > 0; off >>= 1) {
      swc += __shfl_down(swc, off);
      sd  += __shfl_down(sd, off);
    }
    if (lane == 0) { bias[row] = -swc; dvec[row] = sd; }
  } else {
    const int xb = b - 1024;  // 0..255
#pragma unroll
    for (int j = 0; j < 4; ++j) {
      int idx = xb * 1024 + j * 256 + threadIdx.x;
      float4 v = ((const float4*)X)[idx];
      ushort4 a, q;
      a.x = f2bf(v.x); a.y = f2bf(v.y); a.z = f2bf(v.z); a.w = f2bf(v.w);
      q.x = f2bf(v.x * v.x); q.y = f2bf(v.y * v.y);
      q.z = f2bf(v.z * v.z); q.w = f2bf(v.w * v.w);
      ((ushort4*)Xb)[idx] = a;
      ((ushort4*)Qb)[idx] = q;
    }
  }
}

#define GLD16(gp, lp)                                                          \
  __builtin_amdgcn_global_load_lds(                                            \
      (const __attribute__((address_space(1))) unsigned int*)(gp),             \
      (__attribute__((address_space(3))) unsigned int*)(lp), 16, 0, 0)

// Block tile 128(M) x 128(N), BK=32, 4 waves in 2x2, wave tile 64x64 as
// 2x2 frags of 32x32x16 bf16 MFMA. LDS: 2 buffers x 5 streams x 8 KB = 80 KB.
// XOR swizzle: 16B chunk at (row, slot) holds global k-block slot^((row>>1)&3)
// -> conflict-free b128 reads. Grid (32 n, 8 m) = 256 blocks = 1/CU; same-n
// blocks differ by 32 in linear id -> same XCD -> B-panel L2 reuse.
__global__ __launch_bounds__(256, 1) void fgn_gemm(
    const unsigned short* __restrict__ Xb, const unsigned short* __restrict__ Qb,
    const unsigned short* __restrict__ Wb, const unsigned short* __restrict__ I2b,
    const unsigned short* __restrict__ M2b,
    const float* __restrict__ bias, const float* __restrict__ dvec,
    float* __restrict__ out) {
  __shared__ unsigned short lds[2][5][4096];  // 80 KB
  const int t = threadIdx.x;
  const int m0 = blockIdx.y * 128;
  const int n0 = blockIdx.x * 128;

  // staging: thread t -> chunk t (row t>>2, slot t&3) and chunk t+256
  // (row 64+(t>>2), same slot). Global k-block fetched = slot ^ ((row>>1)&3).
  const int srow = t >> 2;
  const int gco  = ((t & 3) ^ ((t >> 3) & 3)) * 8;

  const unsigned short* g0 = Xb  + (size_t)(m0 + srow) * 1024 + gco;
  const unsigned short* g1 = Qb  + (size_t)(m0 + srow) * 1024 + gco;
  const unsigned short* g2 = Wb  + (size_t)(n0 + srow) * 1024 + gco;
  const unsigned short* g3 = I2b + (size_t)(n0 + srow) * 1024 + gco;
  const unsigned short* g4 = M2b + (size_t)(n0 + srow) * 1024 + gco;

#define STAGE(B, S)                                                            \
  do {                                                                         \
    const int ko = (S) * 32;                                                   \
    GLD16(g0 + ko,         &lds[B][0][t * 8]);                                 \
    GLD16(g0 + ko + 65536, &lds[B][0][2048 + t * 8]);                          \
    GLD16(g1 + ko,         &lds[B][1][t * 8]);                                 \
    GLD16(g1 + ko + 65536, &lds[B][1][2048 + t * 8]);                          \
    GLD16(g2 + ko,         &lds[B][2][t * 8]);                                 \
    GLD16(g2 + ko + 65536, &lds[B][2][2048 + t * 8]);                          \
    GLD16(g3 + ko,         &lds[B][3][t * 8]);                                 \
    GLD16(g3 + ko + 65536, &lds[B][3][2048 + t * 8]);                          \
    GLD16(g4 + ko,         &lds[B][4][t * 8]);                                 \
    GLD16(g4 + ko + 65536, &lds[B][4][2048 + t * 8]);                          \
  } while (0)

  const int wave = t >> 6, lane = t & 63;
  const int wx = wave & 1, wy = wave >> 1;
  const int ln = lane & 31, kh = lane >> 5;
  const int sw = (ln >> 1) & 3;  // (row>>1)&3 for all frag rows (mod-4 invariant)

  int aoff[2], boff[2];
#pragma unroll
  for (int i = 0; i < 2; ++i) {
    aoff[i] = (wy * 64 + i * 32 + ln) * 32;
    boff[i] = (wx * 64 + i * 32 + ln) * 32;
  }

  f32x16 accL[2][2], accG[2][2];
#pragma unroll
  for (int i = 0; i < 2; ++i)
#pragma unroll
    for (int j = 0; j < 2; ++j) { accL[i][j] = (f32x16)0.f; accG[i][j] = (f32x16)0.f; }

#define COMPUTE(B)                                                             \
  do {                                                                         \
    _Pragma("unroll")                                                          \
    for (int ks = 0; ks < 2; ++ks) {                                           \
      const int co = ((ks * 2 + kh) ^ sw) * 8;                                 \
      bf16x8 ax[2], aq[2], bw[2], bi[2], bm[2];                                \
      _Pragma("unroll")                                                        \
      for (int i = 0; i < 2; ++i) {                                            \
        ax[i] = *(const bf16x8*)&lds[B][0][aoff[i] + co];                      \
        aq[i] = *(const bf16x8*)&lds[B][1][aoff[i] + co];                      \
        bw[i] = *(const bf16x8*)&lds[B][2][boff[i] + co];                      \
        bi[i] = *(const bf16x8*)&lds[B][3][boff[i] + co];                      \
        bm[i] = *(const bf16x8*)&lds[B][4][boff[i] + co];                      \
      }                                                                        \
      _Pragma("unroll")                                                        \
      for (int mt = 0; mt < 2; ++mt)                                           \
        _Pragma("unroll")                                                      \
        for (int nt = 0; nt < 2; ++nt) {                                       \
          accL[mt][nt] = __builtin_amdgcn_mfma_f32_32x32x16_bf16(              \
              ax[mt], bw[nt], accL[mt][nt], 0, 0, 0);                          \
          accG[mt][nt] = __builtin_amdgcn_mfma_f32_32x32x16_bf16(              \
              aq[mt], bi[nt], accG[mt][nt], 0, 0, 0);                          \
          accG[mt][nt] = __builtin_amdgcn_mfma_f32_32x32x16_bf16(              \
              ax[mt], bm[nt], accG[mt][nt], 0, 0, 0);                          \
        }                                                                      \
    }                                                                          \
  } while (0)

  STAGE(0, 0);
  __syncthreads();
#pragma unroll 1
  for (int p = 0; p < 16; ++p) {
    STAGE(1, 2 * p + 1);          // prefetch next slab while computing current
    COMPUTE(0);
    __syncthreads();              // vmcnt drain covered by ~775cyc of MFMA
    if (p < 15) STAGE(0, 2 * p + 2);
    COMPUTE(1);
    __syncthreads();
  }

  // epilogue: C/D 32x32 layout: col=lane&31, row=(reg&3)+8*(reg>>2)+4*kh
#pragma unroll
  for (int nt = 0; nt < 2; ++nt) {
    int col = n0 + wx * 64 + nt * 32 + ln;
    float bn = bias[col], dn = dvec[col];
#pragma unroll
    for (int mt = 0; mt < 2; ++mt) {
      int rb = m0 + wy * 64 + mt * 32 + 4 * kh;
#pragma unroll
      for (int r = 0; r < 16; ++r) {
        int row = rb + (r & 3) + 8 * (r >> 2);
        float l  = accL[mt][nt][r] + bn;
        float gg = accG[mt][nt][r] + dn;
        out[(size_t)row * 4096 + col] = l * __expf(-gg);
      }
    }
  }
#undef STAGE
#undef COMPUTE
}

extern "C" void kernel_launch(void* const* d_in, const int* in_sizes, int n_in,
                              void* d_out, int out_size, void* d_ws, size_t ws_size,
                              hipStream_t stream) {
  const float* x  = (const float*)d_in[0];
  const float* W  = (const float*)d_in[1];
  const float* C  = (const float*)d_in[2];
  const float* IC = (const float*)d_in[3];
  float* out = (float*)d_out;

  char* ws = (char*)d_ws;
  unsigned short* Wb  = (unsigned short*)(ws);                          // 8 MB
  unsigned short* I2b = (unsigned short*)(ws + (8u << 20));             // 8 MB
  unsigned short* M2b = (unsigned short*)(ws + (16u << 20));            // 8 MB
  unsigned short* Xb  = (unsigned short*)(ws + (24u << 20));            // 2 MB
  unsigned short* Qb  = (unsigned short*)(ws + (26u << 20));            // 2 MB
  float* bias = (float*)(ws + (28u << 20));                             // 16 KB
  float* dvec = (float*)(ws + (28u << 20) + 16384);                     // 16 KB

  hipLaunchKernelGGL(prep, dim3(1280), dim3(256), 0, stream, x, W, C, IC,
                     Wb, I2b, M2b, Xb, Qb, bias, dvec);
  hipLaunchKernelGGL(fgn_gemm, dim3(32, 8), dim3(256), 0, stream,
                     Xb, Qb, Wb, I2b, M2b, bias, dvec, out);
}

// Round 3
// 134.600 us; speedup vs baseline: 1.0335x; 1.0273x over previous
//
#include <hip/hip_runtime.h>
#include <hip/hip_bf16.h>
#include <stdint.h>

// FGN layer: out = (x@W^T + bias) * exp(-( x^2@ic2^T + x@(-2c*ic2)^T + d ))
// R2 post-mortem: latency-bound at 4 waves/CU (MfmaUtil 20%, VALU 8%, all
// pipes idle). R3: 512-thr blocks (8 waves = 2/SIMD), wave-level k-split
// (group 0 = k-step 0, group 1 = k-step 1, LDS reduce in epilogue), x^2
// generated in-register (drops a whole LDS stream: 120->88 KB/slab).

typedef __attribute__((ext_vector_type(8))) __bf16 bf16x8;
typedef __attribute__((ext_vector_type(16))) float f32x16;

__device__ __forceinline__ unsigned short f2bf(float f) {
  union { float f; unsigned int u; } v; v.f = f;
  unsigned int u = v.u;
  unsigned int r = (u + 0x7FFFu + ((u >> 16) & 1u)) >> 16;  // RNE
  return (unsigned short)r;
}

// blocks 0..1023: 4096 O-rows (4/block, one wave each): W->bf16, ic2, -2c*ic2
// (bf16), bias/d reduced fp32. blocks 1024..1279: x->bf16.
__global__ __launch_bounds__(256) void prep(
    const float* __restrict__ X, const float* __restrict__ W,
    const float* __restrict__ C, const float* __restrict__ IC,
    unsigned short* __restrict__ Wb, unsigned short* __restrict__ I2b,
    unsigned short* __restrict__ M2b, unsigned short* __restrict__ Xb,
    float* __restrict__ bias, float* __restrict__ dvec) {
  const int b = blockIdx.x;
  if (b < 1024) {
    const int wave = threadIdx.x >> 6;
    const int lane = threadIdx.x & 63;
    const int row  = b * 4 + wave;
    const float4* W4 = (const float4*)W + (size_t)row * 256;
    const float4* C4 = (const float4*)C + (size_t)row * 256;
    const float4* I4 = (const float4*)IC + (size_t)row * 256;
    ushort4* Wo = (ushort4*)Wb + (size_t)row * 256;
    ushort4* Io = (ushort4*)I2b + (size_t)row * 256;
    ushort4* Mo = (ushort4*)M2b + (size_t)row * 256;
    float swc = 0.f, sd = 0.f;
#pragma unroll
    for (int p = 0; p < 4; ++p) {
      int idx = lane + p * 64;
      float4 w = W4[idx], c = C4[idx], ic = I4[idx];
      float i2x = ic.x * ic.x, i2y = ic.y * ic.y, i2z = ic.z * ic.z, i2w = ic.w * ic.w;
      swc += w.x * c.x + w.y * c.y + w.z * c.z + w.w * c.w;
      sd  += c.x * c.x * i2x + c.y * c.y * i2y + c.z * c.z * i2z + c.w * c.w * i2w;
      ushort4 a, bb, m;
      a.x = f2bf(w.x); a.y = f2bf(w.y); a.z = f2bf(w.z); a.w = f2bf(w.w);
      bb.x = f2bf(i2x); bb.y = f2bf(i2y); bb.z = f2bf(i2z); bb.w = f2bf(i2w);
      m.x = f2bf(-2.f * c.x * i2x); m.y = f2bf(-2.f * c.y * i2y);
      m.z = f2bf(-2.f * c.z * i2z); m.w = f2bf(-2.f * c.w * i2w);
      Wo[idx] = a; Io[idx] = bb; Mo[idx] = m;
    }
#pragma unroll
    for (int off = 32; off > 0; off >>= 1) {
      swc += __shfl_down(swc, off);
      sd  += __shfl_down(sd, off);
    }
    if (lane == 0) { bias[row] = -swc; dvec[row] = sd; }
  } else {
    const int xb = b - 1024;  // 0..255
#pragma unroll
    for (int j = 0; j < 4; ++j) {
      int idx = xb * 1024 + j * 256 + threadIdx.x;
      float4 v = ((const float4*)X)[idx];
      ushort4 a;
      a.x = f2bf(v.x); a.y = f2bf(v.y); a.z = f2bf(v.z); a.w = f2bf(v.w);
      ((ushort4*)Xb)[idx] = a;
    }
  }
}

#define GLD16(gp, lp)                                                          \
  __builtin_amdgcn_global_load_lds(                                            \
      (const __attribute__((address_space(1))) unsigned int*)(gp),             \
      (__attribute__((address_space(3))) unsigned int*)(lp), 16, 0, 0)

// 128x128 block tile, BK=32, 512 threads = 8 waves. Wave w: kg = w>>2 picks
// the MFMA k-step (0/1) of each slab, wq = w&3 picks the 32-wide N strip.
// Wave tile 128M x 32N = 4 m-frags of 32x32x16. Epilogue: kg=1 partials
// reduced into kg=0 via LDS (two 64 KB rounds reusing the staging buffers).
// LDS: 2 bufs x 4 streams x 8 KB = 64 KB. XOR swizzle slot^=(row>>1)&3.
__global__ __launch_bounds__(512, 2) void fgn_gemm(
    const unsigned short* __restrict__ Xb, const unsigned short* __restrict__ Wb,
    const unsigned short* __restrict__ I2b, const unsigned short* __restrict__ M2b,
    const float* __restrict__ bias, const float* __restrict__ dvec,
    float* __restrict__ out) {
  __shared__ unsigned char smem[65536];
#define SBUF(B, S) ((unsigned short*)(smem + (B) * 32768 + (S) * 8192))
  const int t = threadIdx.x;
  const int m0 = blockIdx.y * 128;
  const int n0 = blockIdx.x * 128;

  // staging: thread t -> LDS row t>>2 (64 B/row), slot t&3; global chunk
  // fetched = slot ^ ((row>>1)&3)  (conflict-breaking XOR swizzle)
  const int srow = t >> 2;
  const int gco  = ((t & 3) ^ ((srow >> 1) & 3)) * 8;
  const unsigned short* gx = Xb  + (size_t)(m0 + srow) * 1024 + gco;
  const unsigned short* gw = Wb  + (size_t)(n0 + srow) * 1024 + gco;
  const unsigned short* gi = I2b + (size_t)(n0 + srow) * 1024 + gco;
  const unsigned short* gm = M2b + (size_t)(n0 + srow) * 1024 + gco;

#define STAGE(B, KO)                                                           \
  do {                                                                         \
    GLD16(gx + (KO), SBUF(B, 0) + t * 8);                                      \
    GLD16(gw + (KO), SBUF(B, 1) + t * 8);                                      \
    GLD16(gi + (KO), SBUF(B, 2) + t * 8);                                      \
    GLD16(gm + (KO), SBUF(B, 3) + t * 8);                                      \
  } while (0)

  const int wave = t >> 6;
  const int kg = wave >> 2;       // k-step group
  const int wq = wave & 3;        // N strip
  const int lane = t & 63;
  const int ln = lane & 31, kh = lane >> 5;
  const int sw = (ln >> 1) & 3;
  const int co = (((kg << 1) | kh) ^ sw) * 8;  // element offset in 32-el row

  int aoff[4];
#pragma unroll
  for (int mt = 0; mt < 4; ++mt) aoff[mt] = (mt * 32 + ln) * 32 + co;
  const int boff = (wq * 32 + ln) * 32 + co;

  f32x16 accL[4], accG[4];
#pragma unroll
  for (int mt = 0; mt < 4; ++mt) { accL[mt] = (f32x16)0.f; accG[mt] = (f32x16)0.f; }

#define COMPUTE(B)                                                             \
  do {                                                                         \
    const unsigned short* p0 = SBUF(B, 0);                                     \
    bf16x8 ax[4], aq[4];                                                       \
    _Pragma("unroll")                                                          \
    for (int mt = 0; mt < 4; ++mt) ax[mt] = *(const bf16x8*)(p0 + aoff[mt]);   \
    bf16x8 bw = *(const bf16x8*)(SBUF(B, 1) + boff);                           \
    bf16x8 bi = *(const bf16x8*)(SBUF(B, 2) + boff);                           \
    bf16x8 bm = *(const bf16x8*)(SBUF(B, 3) + boff);                           \
    _Pragma("unroll")                                                          \
    for (int mt = 0; mt < 4; ++mt) {                                           \
      bf16x8 a = ax[mt], q;                                                    \
      _Pragma("unroll")                                                        \
      for (int j = 0; j < 8; ++j) { float f = (float)a[j]; q[j] = (__bf16)(f * f); } \
      aq[mt] = q;                                                              \
    }                                                                          \
    _Pragma("unroll")                                                          \
    for (int mt = 0; mt < 4; ++mt)                                             \
      accL[mt] = __builtin_amdgcn_mfma_f32_32x32x16_bf16(ax[mt], bw, accL[mt], 0, 0, 0); \
    _Pragma("unroll")                                                          \
    for (int mt = 0; mt < 4; ++mt)                                             \
      accG[mt] = __builtin_amdgcn_mfma_f32_32x32x16_bf16(aq[mt], bi, accG[mt], 0, 0, 0); \
    _Pragma("unroll")                                                          \
    for (int mt = 0; mt < 4; ++mt)                                             \
      accG[mt] = __builtin_amdgcn_mfma_f32_32x32x16_bf16(ax[mt], bm, accG[mt], 0, 0, 0); \
  } while (0)

  STAGE(0, 0);
  __syncthreads();
#pragma unroll 1
  for (int p = 0; p < 32; p += 2) {
    STAGE(1, (p + 1) * 32);            // prefetch next slab into other buffer
    COMPUTE(0);
    __syncthreads();
    if (p + 2 < 32) STAGE(0, (p + 2) * 32);
    COMPUTE(1);
    __syncthreads();
  }

  // ---- epilogue: reduce kg=1 partials into kg=0, apply bias/exp, store ----
  float* epi = (float*)smem;
  const int col = n0 + wq * 32 + ln;
  float bn = 0.f, dn = 0.f;
  if (kg == 0) { bn = bias[col]; dn = dvec[col]; }

  // round 1: accL (4 waves x 16 KB = 64 KB)
  if (kg == 1) {
    float* base = epi + wq * 4096 + lane * 16;
#pragma unroll
    for (int mt = 0; mt < 4; ++mt) *(f32x16*)(base + mt * 1024) = accL[mt];
  }
  __syncthreads();
  if (kg == 0) {
    const float* base = epi + wq * 4096 + lane * 16;
#pragma unroll
    for (int mt = 0; mt < 4; ++mt) accL[mt] += *(const f32x16*)(base + mt * 1024);
  }
  __syncthreads();
  // round 2: accG
  if (kg == 1) {
    float* base = epi + wq * 4096 + lane * 16;
#pragma unroll
    for (int mt = 0; mt < 4; ++mt) *(f32x16*)(base + mt * 1024) = accG[mt];
  }
  __syncthreads();
  if (kg == 0) {
    const float* base = epi + wq * 4096 + lane * 16;
#pragma unroll
    for (int mt = 0; mt < 4; ++mt) {
      accG[mt] += *(const f32x16*)(base + mt * 1024);
      // C/D 32x32 layout: col=lane&31, row=(reg&3)+8*(reg>>2)+4*(lane>>5)
      int rb = m0 + mt * 32 + 4 * kh;
#pragma unroll
      for (int r = 0; r < 16; ++r) {
        int row = rb + (r & 3) + 8 * (r >> 2);
        float l = accL[mt][r] + bn;
        float g = accG[mt][r] + dn;
        out[(size_t)row * 4096 + col] = l * __expf(-g);
      }
    }
  }
#undef STAGE
#undef COMPUTE
#undef SBUF
}

extern "C" void kernel_launch(void* const* d_in, const int* in_sizes, int n_in,
                              void* d_out, int out_size, void* d_ws, size_t ws_size,
                              hipStream_t stream) {
  const float* x  = (const float*)d_in[0];
  const float* W  = (const float*)d_in[1];
  const float* C  = (const float*)d_in[2];
  const float* IC = (const float*)d_in[3];
  float* out = (float*)d_out;

  char* ws = (char*)d_ws;
  unsigned short* Wb  = (unsigned short*)(ws);                          // 8 MB
  unsigned short* I2b = (unsigned short*)(ws + (8u << 20));             // 8 MB
  unsigned short* M2b = (unsigned short*)(ws + (16u << 20));            // 8 MB
  unsigned short* Xb  = (unsigned short*)(ws + (24u << 20));            // 2 MB
  float* bias = (float*)(ws + (26u << 20));                             // 16 KB
  float* dvec = (float*)(ws + (26u << 20) + 16384);                     // 16 KB

  hipLaunchKernelGGL(prep, dim3(1280), dim3(256), 0, stream, x, W, C, IC,
                     Wb, I2b, M2b, Xb, bias, dvec);
  hipLaunchKernelGGL(fgn_gemm, dim3(32, 8), dim3(512), 0, stream,
                     Xb, Wb, I2b, M2b, bias, dvec, out);
}

// Round 4
// 130.856 us; speedup vs baseline: 1.0630x; 1.0286x over previous
//
#include <hip/hip_runtime.h>
#include <hip/hip_bf16.h>
#include <stdint.h>

// FGN layer: out = (x@W^T + bias) * exp(-( x^2@ic2^T + x@(-2c*ic2)^T + d ))
// R3 post-mortem: 3 structures all ~44-45us with grid=256 (1 block/CU) --
// barrier-drain stall with no co-resident work. R4: 128Mx64N tile, grid
// (64,8)=512 blocks = 2/CU so independent blocks hide each other's drains
// (m114 co-scheduling). 4 waves = kg(2) x wq(2), wave tile 128Mx32N.

typedef __attribute__((ext_vector_type(8))) __bf16 bf16x8;
typedef __attribute__((ext_vector_type(16))) float f32x16;

__device__ __forceinline__ unsigned short f2bf(float f) {
  union { float f; unsigned int u; } v; v.f = f;
  unsigned int u = v.u;
  unsigned int r = (u + 0x7FFFu + ((u >> 16) & 1u)) >> 16;  // RNE
  return (unsigned short)r;
}

// blocks 0..1023: 4096 O-rows (4/block, one wave each): W->bf16, ic2, -2c*ic2
// (bf16), bias/d reduced fp32. blocks 1024..1279: x->bf16.
__global__ __launch_bounds__(256) void prep(
    const float* __restrict__ X, const float* __restrict__ W,
    const float* __restrict__ C, const float* __restrict__ IC,
    unsigned short* __restrict__ Wb, unsigned short* __restrict__ I2b,
    unsigned short* __restrict__ M2b, unsigned short* __restrict__ Xb,
    float* __restrict__ bias, float* __restrict__ dvec) {
  const int b = blockIdx.x;
  if (b < 1024) {
    const int wave = threadIdx.x >> 6;
    const int lane = threadIdx.x & 63;
    const int row  = b * 4 + wave;
    const float4* W4 = (const float4*)W + (size_t)row * 256;
    const float4* C4 = (const float4*)C + (size_t)row * 256;
    const float4* I4 = (const float4*)IC + (size_t)row * 256;
    ushort4* Wo = (ushort4*)Wb + (size_t)row * 256;
    ushort4* Io = (ushort4*)I2b + (size_t)row * 256;
    ushort4* Mo = (ushort4*)M2b + (size_t)row * 256;
    float swc = 0.f, sd = 0.f;
#pragma unroll
    for (int p = 0; p < 4; ++p) {
      int idx = lane + p * 64;
      float4 w = W4[idx], c = C4[idx], ic = I4[idx];
      float i2x = ic.x * ic.x, i2y = ic.y * ic.y, i2z = ic.z * ic.z, i2w = ic.w * ic.w;
      swc += w.x * c.x + w.y * c.y + w.z * c.z + w.w * c.w;
      sd  += c.x * c.x * i2x + c.y * c.y * i2y + c.z * c.z * i2z + c.w * c.w * i2w;
      ushort4 a, bb, m;
      a.x = f2bf(w.x); a.y = f2bf(w.y); a.z = f2bf(w.z); a.w = f2bf(w.w);
      bb.x = f2bf(i2x); bb.y = f2bf(i2y); bb.z = f2bf(i2z); bb.w = f2bf(i2w);
      m.x = f2bf(-2.f * c.x * i2x); m.y = f2bf(-2.f * c.y * i2y);
      m.z = f2bf(-2.f * c.z * i2z); m.w = f2bf(-2.f * c.w * i2w);
      Wo[idx] = a; Io[idx] = bb; Mo[idx] = m;
    }
#pragma unroll
    for (int off = 32; off > 0; off >>= 1) {
      swc += __shfl_down(swc, off);
      sd  += __shfl_down(sd, off);
    }
    if (lane == 0) { bias[row] = -swc; dvec[row] = sd; }
  } else {
    const int xb = b - 1024;  // 0..255
#pragma unroll
    for (int j = 0; j < 4; ++j) {
      int idx = xb * 1024 + j * 256 + threadIdx.x;
      float4 v = ((const float4*)X)[idx];
      ushort4 a;
      a.x = f2bf(v.x); a.y = f2bf(v.y); a.z = f2bf(v.z); a.w = f2bf(v.w);
      ((ushort4*)Xb)[idx] = a;
    }
  }
}

#define GLD16(gp, lp)                                                          \
  __builtin_amdgcn_global_load_lds(                                            \
      (const __attribute__((address_space(1))) unsigned int*)(gp),             \
      (__attribute__((address_space(3))) unsigned int*)(lp), 16, 0, 0)

// 128M x 64N block tile, BK=32, 256 threads = 4 waves: kg = wave>>1 picks the
// MFMA k-step (0/1), wq = wave&1 picks the 32-wide N strip. Wave tile 128Mx32N
// = 4 m-frags of 32x32x16. kg=1 partials reduced into kg=0 via LDS epilogue.
// LDS: 2 bufs x (X 8 KB + 3 B-streams x 4 KB) = 40 KB. XOR swizzle
// slot ^= (row>>1)&3 for conflict-free b128 reads. Grid (64 n, 8 m) = 512
// blocks = 2/CU; same-n blocks all land on one XCD (64*m % 8 == 0).
__global__ __launch_bounds__(256, 2) void fgn_gemm(
    const unsigned short* __restrict__ Xb, const unsigned short* __restrict__ Wb,
    const unsigned short* __restrict__ I2b, const unsigned short* __restrict__ M2b,
    const float* __restrict__ bias, const float* __restrict__ dvec,
    float* __restrict__ out) {
  __shared__ unsigned char smem[40960];
#define XBUF(B)    ((unsigned short*)(smem + (B) * 20480))
#define BBUF(B, S) ((unsigned short*)(smem + (B) * 20480 + 8192 + (S) * 4096))
  const int t = threadIdx.x;
  const int m0 = blockIdx.y * 128;
  const int n0 = blockIdx.x * 64;

  // staging (per slab): X = 512 chunks of 16B (2/thread), each B stream = 256
  // chunks (1/thread). chunk c -> row c>>2, slot c&3; global k-chunk fetched
  // = slot ^ ((row>>1)&3).
  const int r0 = t >> 2;            // X chunk t row (0..63), B row (0..63)
  const int r1 = (t + 256) >> 2;    // X chunk t+256 row (64..127)
  const int gc0 = ((t & 3) ^ ((r0 >> 1) & 3)) * 8;
  const int gc1 = ((t & 3) ^ ((r1 >> 1) & 3)) * 8;
  const unsigned short* gx0 = Xb + (size_t)(m0 + r0) * 1024 + gc0;
  const unsigned short* gx1 = Xb + (size_t)(m0 + r1) * 1024 + gc1;
  const unsigned short* gw = Wb  + (size_t)(n0 + r0) * 1024 + gc0;
  const unsigned short* gi = I2b + (size_t)(n0 + r0) * 1024 + gc0;
  const unsigned short* gm = M2b + (size_t)(n0 + r0) * 1024 + gc0;

#define STAGE(B, KO)                                                           \
  do {                                                                         \
    GLD16(gx0 + (KO), XBUF(B) + t * 8);                                        \
    GLD16(gx1 + (KO), XBUF(B) + 2048 + t * 8);                                 \
    GLD16(gw + (KO), BBUF(B, 0) + t * 8);                                      \
    GLD16(gi + (KO), BBUF(B, 1) + t * 8);                                      \
    GLD16(gm + (KO), BBUF(B, 2) + t * 8);                                      \
  } while (0)

  const int wave = t >> 6;
  const int kg = wave >> 1;        // k-step group
  const int wq = wave & 1;         // N strip
  const int lane = t & 63;
  const int ln = lane & 31, kh = lane >> 5;
  const int co = (((kg << 1) | kh) ^ ((ln >> 1) & 3)) * 8;

  int aoff[4];
#pragma unroll
  for (int mt = 0; mt < 4; ++mt) aoff[mt] = (mt * 32 + ln) * 32 + co;
  const int boff = (wq * 32 + ln) * 32 + co;

  f32x16 accL[4], accG[4];
#pragma unroll
  for (int mt = 0; mt < 4; ++mt) { accL[mt] = (f32x16)0.f; accG[mt] = (f32x16)0.f; }

#define COMPUTE(B)                                                             \
  do {                                                                         \
    const unsigned short* px = XBUF(B);                                        \
    bf16x8 ax[4], aq[4];                                                       \
    _Pragma("unroll")                                                          \
    for (int mt = 0; mt < 4; ++mt) ax[mt] = *(const bf16x8*)(px + aoff[mt]);   \
    bf16x8 bw = *(const bf16x8*)(BBUF(B, 0) + boff);                           \
    bf16x8 bi = *(const bf16x8*)(BBUF(B, 1) + boff);                           \
    bf16x8 bm = *(const bf16x8*)(BBUF(B, 2) + boff);                           \
    _Pragma("unroll")                                                          \
    for (int mt = 0; mt < 4; ++mt) {                                           \
      bf16x8 a = ax[mt], q;                                                    \
      _Pragma("unroll")                                                        \
      for (int j = 0; j < 8; ++j) { float f = (float)a[j]; q[j] = (__bf16)(f * f); } \
      aq[mt] = q;                                                              \
    }                                                                          \
    _Pragma("unroll")                                                          \
    for (int mt = 0; mt < 4; ++mt)                                             \
      accL[mt] = __builtin_amdgcn_mfma_f32_32x32x16_bf16(ax[mt], bw, accL[mt], 0, 0, 0); \
    _Pragma("unroll")                                                          \
    for (int mt = 0; mt < 4; ++mt)                                             \
      accG[mt] = __builtin_amdgcn_mfma_f32_32x32x16_bf16(aq[mt], bi, accG[mt], 0, 0, 0); \
    _Pragma("unroll")                                                          \
    for (int mt = 0; mt < 4; ++mt)                                             \
      accG[mt] = __builtin_amdgcn_mfma_f32_32x32x16_bf16(ax[mt], bm, accG[mt], 0, 0, 0); \
  } while (0)

  STAGE(0, 0);
  __syncthreads();
#pragma unroll 1
  for (int p = 0; p < 32; p += 2) {
    STAGE(1, (p + 1) * 32);            // prefetch next slab into other buffer
    COMPUTE(0);
    __syncthreads();
    if (p + 2 < 32) STAGE(0, (p + 2) * 32);
    COMPUTE(1);
    __syncthreads();
  }

  // ---- epilogue: reduce kg=1 partials into kg=0, apply bias/exp, store ----
  // LDS slot (wq, mt, lane): byte addr = wq*16384 + mt*4096 + lane*64
  float* epi = (float*)smem;
  const int col = n0 + wq * 32 + ln;
  float bn = 0.f, dn = 0.f;
  if (kg == 0) { bn = bias[col]; dn = dvec[col]; }
  {
    float* base = (float*)(smem + wq * 16384 + lane * 64);
    // round 1: accL
    if (kg == 1) {
#pragma unroll
      for (int mt = 0; mt < 4; ++mt) *(f32x16*)(base + mt * 1024) = accL[mt];
    }
    __syncthreads();
    if (kg == 0) {
#pragma unroll
      for (int mt = 0; mt < 4; ++mt) accL[mt] += *(const f32x16*)(base + mt * 1024);
    }
    __syncthreads();
    // round 2: accG
    if (kg == 1) {
#pragma unroll
      for (int mt = 0; mt < 4; ++mt) *(f32x16*)(base + mt * 1024) = accG[mt];
    }
    __syncthreads();
    if (kg == 0) {
#pragma unroll
      for (int mt = 0; mt < 4; ++mt) {
        accG[mt] += *(const f32x16*)(base + mt * 1024);
        // C/D 32x32 layout: col=lane&31, row=(reg&3)+8*(reg>>2)+4*(lane>>5)
        int rb = m0 + mt * 32 + 4 * kh;
#pragma unroll
        for (int r = 0; r < 16; ++r) {
          int row = rb + (r & 3) + 8 * (r >> 2);
          float l = accL[mt][r] + bn;
          float g = accG[mt][r] + dn;
          out[(size_t)row * 4096 + col] = l * __expf(-g);
        }
      }
    }
  }
#undef STAGE
#undef COMPUTE
#undef XBUF
#undef BBUF
}

extern "C" void kernel_launch(void* const* d_in, const int* in_sizes, int n_in,
                              void* d_out, int out_size, void* d_ws, size_t ws_size,
                              hipStream_t stream) {
  const float* x  = (const float*)d_in[0];
  const float* W  = (const float*)d_in[1];
  const float* C  = (const float*)d_in[2];
  const float* IC = (const float*)d_in[3];
  float* out = (float*)d_out;

  char* ws = (char*)d_ws;
  unsigned short* Wb  = (unsigned short*)(ws);                          // 8 MB
  unsigned short* I2b = (unsigned short*)(ws + (8u << 20));             // 8 MB
  unsigned short* M2b = (unsigned short*)(ws + (16u << 20));            // 8 MB
  unsigned short* Xb  = (unsigned short*)(ws + (24u << 20));            // 2 MB
  float* bias = (float*)(ws + (26u << 20));                             // 16 KB
  float* dvec = (float*)(ws + (26u << 20) + 16384);                     // 16 KB

  hipLaunchKernelGGL(prep, dim3(1280), dim3(256), 0, stream, x, W, C, IC,
                     Wb, I2b, M2b, Xb, bias, dvec);
  hipLaunchKernelGGL(fgn_gemm, dim3(64, 8), dim3(256), 0, stream,
                     Xb, Wb, I2b, M2b, bias, dvec, out);
}